// Round 10
// baseline (142.094 us; speedup 1.0000x reference)
//
#include <hip/hip_runtime.h>

#define M_ROWS 16384
#define DIMX   1024
#define CD     12
#define KCB    4096
#define PADW   60   // padded dwords per float4-position fragment (48 data + 12 pad)
#define NSLAB  512  // one hist slab per k_body block

// ---------- Kernel A: h = x @ W_in + b_in ; writes h and oidx ----------
// Arithmetic (FMA order k,e,d; butterfly ofs 1..32; +bin at end) is bit-identical
// to the round-1/2 version that produced exact index match. Also zeroes the two
// scalar accumulators (pse, com).
__global__ __launch_bounds__(256, 2) void k_hproj(
    const float* __restrict__ x, const float* __restrict__ Win,
    const float* __restrict__ bin, float* __restrict__ h, float* __restrict__ oidx,
    float* __restrict__ scal)
{
  if (blockIdx.x == 0 && threadIdx.x == 0) {
    scal[0] = 0.f; scal[1] = 0.f;   // pse, com
  }

  __shared__ __align__(16) float w[256 * PADW];   // 60 KB
  for (int f = threadIdx.x; f < 256 * 12; f += 256) {
    const int P = f / 12, c = f % 12;
    float4 v = reinterpret_cast<const float4*>(Win)[f];
    *reinterpret_cast<float4*>(&w[P * PADW + 4 * c]) = v;
  }
  __syncthreads();

  const int wave = threadIdx.x >> 6;
  const int lane = threadIdx.x & 63;
  const int g    = blockIdx.x * 4 + wave;         // 0..2047, 8 rows per wave

  float bb[CD];
#pragma unroll
  for (int d = 0; d < CD; ++d) bb[d] = bin[d];

  for (int it = 0; it < 4; ++it) {                // 2 rows per iteration
    const int row0 = g * 8 + it * 2;
    const float4* xr0 = reinterpret_cast<const float4*>(x + (size_t)row0 * DIMX);
    const float4* xr1 = reinterpret_cast<const float4*>(x + (size_t)(row0 + 1) * DIMX);
    float a0[CD], a1[CD];
#pragma unroll
    for (int d = 0; d < CD; ++d) { a0[d] = 0.f; a1[d] = 0.f; }

#pragma unroll
    for (int k = 0; k < 4; ++k) {
      const int P = lane + 64 * k;
      float4 xv0 = xr0[P];
      float4 xv1 = xr1[P];
      const float4* wf = reinterpret_cast<const float4*>(&w[P * PADW]);
      float4 wq[12];
#pragma unroll
      for (int c = 0; c < 12; ++c) wq[c] = wf[c];
      const float* wfl = reinterpret_cast<const float*>(wq);
      float xe0[4] = {xv0.x, xv0.y, xv0.z, xv0.w};
      float xe1[4] = {xv1.x, xv1.y, xv1.z, xv1.w};
#pragma unroll
      for (int e = 0; e < 4; ++e)
#pragma unroll
        for (int d = 0; d < CD; ++d) {
          const float wv = wfl[e * CD + d];
          a0[d] = fmaf(xe0[e], wv, a0[d]);
          a1[d] = fmaf(xe1[e], wv, a1[d]);
        }
    }
#pragma unroll
    for (int ofs = 1; ofs < 64; ofs <<= 1)
#pragma unroll
      for (int d = 0; d < CD; ++d) {
        a0[d] += __shfl_xor(a0[d], ofs, 64);
        a1[d] += __shfl_xor(a1[d], ofs, 64);
      }

    if (lane == 0) {
      int i0 = 0, i1 = 0;
#pragma unroll
      for (int d = 0; d < CD; ++d) {
        const float h0 = a0[d] + bb[d];
        const float h1 = a1[d] + bb[d];
        h[(size_t)row0 * CD + d]       = h0;
        h[(size_t)(row0 + 1) * CD + d] = h1;
        i0 |= (h0 > 0.f) ? (1 << d) : 0;
        i1 |= (h1 > 0.f) ? (1 << d) : 0;
      }
      oidx[row0]     = (float)i0;
      oidx[row0 + 1] = (float)i1;
    }
  }
}

// ---------- Kernel B: fused out-projection + entropy/commit + histogram ----------
// 512 threads, 32 rows per block.
// Phase 0: q = sigmoid(40h) computed ONCE per block (threads 0..383, one (row,d)
//          each, coalesced h load, one exp) -> LDS sq[32][16]; pse/com reduced here.
// Phase A: thread owns 2 output cols (wreg = 24 regs, under the ~56-VGPR RA cap).
// Phase B: 8 waves; wave w owns hist m in [8w, 8w+8): per row just 3 broadcast
//          ds_read_b128 + straight-line trees + 8 FMA. No shfl chain, no exp.
__global__ __launch_bounds__(512) void k_body(
    const float* __restrict__ h, const float* __restrict__ Wout,
    const float* __restrict__ bout, const float* __restrict__ oidx,
    float* __restrict__ out, float* __restrict__ hist_part,
    float* __restrict__ scal)
{
  __shared__ __align__(16) float sq[32 * 16];    // q[row][d], row-padded to 16
  const int t    = threadIdx.x;          // 0..511
  const int bid  = blockIdx.x;
  const int row0 = bid * 32;

  // ---------------- Phase 0: q-tree once per block ----------------
  if (t < 384) {                          // waves 0..5, one (row,d) per thread
    const float hv  = h[(size_t)row0 * CD + t];   // coalesced 384 floats
    const float ax  = fabsf(40.f * hv);
    const float e2  = __expf(-ax);
    const float s1  = 1.f + e2;
    const float inv = 1.f / s1;
    const float qv  = (hv > 0.f) ? inv : e2 * inv;          // sigmoid(40 h)
    sq[(t / 12) * 16 + (t % 12)] = qv;
    float pse_c = __logf(s1) + ax * e2 * inv;               // per-dim entropy
    const float dd = fabsf(hv) - 1.f;
    float com_c = dd * dd;
#pragma unroll
    for (int ofs = 1; ofs < 64; ofs <<= 1) {
      pse_c += __shfl_xor(pse_c, ofs, 64);
      com_c += __shfl_xor(com_c, ofs, 64);
    }
    if ((t & 63) == 0) { atomicAdd(&scal[0], pse_c); atomicAdd(&scal[1], com_c); }
  }

  // ---------------- Phase A: out = sign(h) @ W_out + b_out ----------------
  {
    float w0[CD], w1[CD];
#pragma unroll
    for (int d = 0; d < CD; ++d) {
      float2 v = *reinterpret_cast<const float2*>(Wout + d * DIMX + 2 * t);
      w0[d] = v.x; w1[d] = v.y;
    }
    const float2 b2 = *reinterpret_cast<const float2*>(bout + 2 * t);

    for (int i = 0; i < 32; ++i) {
      const int row = row0 + i;
      const int idx = (int)oidx[row];    // block-uniform scalar load
      float o0 = b2.x, o1 = b2.y;
#pragma unroll
      for (int d = 0; d < CD; ++d) {
        const float s = ((idx >> d) & 1) ? 1.f : -1.f;
        o0 = fmaf(s, w0[d], o0);
        o1 = fmaf(s, w1[d], o1);
      }
      *reinterpret_cast<float2*>(out + (size_t)row * DIMX + 2 * t) = make_float2(o0, o1);
    }
  }

  __syncthreads();                        // sq ready for all waves

  // ---------------- Phase B: factorized histogram ----------------
  const int lane = t & 63;
  const int w8   = t >> 6;                // wave id 0..7; m in [8*w8, 8*w8+8)

  float c0=0.f,c1=0.f,c2=0.f,c3=0.f,c4=0.f,c5=0.f,c6=0.f,c7=0.f;

  for (int i = 0; i < 32; ++i) {
    const float4 qa = *reinterpret_cast<const float4*>(&sq[i * 16]);      // q0..q3
    const float4 qb = *reinterpret_cast<const float4*>(&sq[i * 16 + 4]);  // q4..q7
    const float4 qc = *reinterpret_cast<const float4*>(&sq[i * 16 + 8]);  // q8..q11

    // A over the low 6 bits (lane-dependent)
    float A = ((lane >> 0) & 1) ? qa.x : 1.f - qa.x;
    A      *= ((lane >> 1) & 1) ? qa.y : 1.f - qa.y;
    A      *= ((lane >> 2) & 1) ? qa.z : 1.f - qa.z;
    A      *= ((lane >> 3) & 1) ? qa.w : 1.f - qa.w;
    A      *= ((lane >> 4) & 1) ? qb.x : 1.f - qb.x;
    A      *= ((lane >> 5) & 1) ? qb.y : 1.f - qb.y;

    // E = A * C over dims 6..8
    const float t6 = 1.f - qb.z, t7 = 1.f - qb.w, t8 = 1.f - qc.x;
    const float u0 = t6 * t7, u1 = qb.z * t7, u2 = t6 * qb.w, u3 = qb.z * qb.w;
    const float E0 = A * (u0 * t8),   E1 = A * (u1 * t8),   E2 = A * (u2 * t8),   E3 = A * (u3 * t8);
    const float E4 = A * (u0 * qc.x), E5 = A * (u1 * qc.x), E6 = A * (u2 * qc.x), E7 = A * (u3 * qc.x);

    // this wave's single D value over dims 9..11 (m>>3 == w8)
    const float vw = (((w8 & 1) ? qc.y : 1.f - qc.y) * ((w8 & 2) ? qc.z : 1.f - qc.z));
    const float Dw = vw * ((w8 & 4) ? qc.w : 1.f - qc.w);

    c0 = fmaf(E0, Dw, c0); c1 = fmaf(E1, Dw, c1); c2 = fmaf(E2, Dw, c2); c3 = fmaf(E3, Dw, c3);
    c4 = fmaf(E4, Dw, c4); c5 = fmaf(E5, Dw, c5); c6 = fmaf(E6, Dw, c6); c7 = fmaf(E7, Dw, c7);
  }

  // disjoint coalesced slab write: index = (8*w8 + e)*64 + lane
  float* hp = hist_part + (size_t)bid * KCB + (size_t)w8 * 512 + lane;
  hp[0*64] = c0; hp[1*64] = c1; hp[2*64] = c2; hp[3*64] = c3;
  hp[4*64] = c4; hp[5*64] = c5; hp[6*64] = c6; hp[7*64] = c7;
}

// ---------- Kernel C: stage-1 slab reduction (128 blocks) ----------
__global__ __launch_bounds__(256) void k_hr1(
    const float* __restrict__ hist_part, float* __restrict__ part2)
{
  const int j0    = (blockIdx.x & 7) * 512 + threadIdx.x;
  const int chunk = blockIdx.x >> 3;              // 0..15
  const int s0    = chunk * (NSLAB / 16);
  float acc0 = 0.f, acc1 = 0.f;
#pragma unroll 4
  for (int s = 0; s < NSLAB / 16; ++s) {
    const float* hp = hist_part + (size_t)(s0 + s) * KCB;
    acc0 += hp[j0];
    acc1 += hp[j0 + 256];
  }
  part2[(size_t)chunk * KCB + j0]       = acc0;
  part2[(size_t)chunk * KCB + j0 + 256] = acc1;
}

// ---------- Kernel D: final codebook entropy + aux (single block) ----------
__global__ __launch_bounds__(256) void k_fin(
    const float* __restrict__ part2, const float* __restrict__ scal,
    float* __restrict__ aux)
{
  const int t = threadIdx.x;
  float term = 0.f;
#pragma unroll
  for (int k = 0; k < 16; ++k) {
    const int j = t + 256 * k;
    float a = 0.f;
#pragma unroll
    for (int c = 0; c < 16; ++c) a += part2[(size_t)c * KCB + j];
    a *= (1.f / 16384.f);
    term -= a * __logf(a + 1e-10f);
  }
#pragma unroll
  for (int ofs = 1; ofs < 64; ofs <<= 1) term += __shfl_xor(term, ofs, 64);
  __shared__ float sw[4];
  if ((t & 63) == 0) sw[t >> 6] = term;
  __syncthreads();
  if (t == 0) {
    const float cbe = sw[0] + sw[1] + sw[2] + sw[3];
    aux[0] = scal[0] * (1.f / 16384.f) - cbe + scal[1] * (1.f / 196608.f);
  }
}

extern "C" void kernel_launch(void* const* d_in, const int* in_sizes, int n_in,
                              void* d_out, int out_size, void* d_ws, size_t ws_size,
                              hipStream_t stream)
{
  const float* x    = (const float*)d_in[0];
  const float* Win  = (const float*)d_in[1];
  const float* bin  = (const float*)d_in[2];
  const float* Wout = (const float*)d_in[3];
  const float* bout = (const float*)d_in[4];

  float* out  = (float*)d_out;                       // [16384 x 1024]
  float* oidx = out + (size_t)M_ROWS * DIMX;         // [16384]
  float* aux  = oidx + M_ROWS;                       // [1]

  float* ws        = (float*)d_ws;
  float* h         = ws;                             // 196608 floats
  float* scal      = ws + (size_t)M_ROWS * CD;       // pse, com (pad 16)
  float* part2     = scal + 16;                      // 16 * 4096 floats
  float* hist_part = part2 + 16 * KCB;               // NSLAB * 4096 floats

  k_hproj<<<512, 256, 0, stream>>>(x, Win, bin, h, oidx, scal);
  k_body <<<NSLAB, 512, 0, stream>>>(h, Wout, bout, oidx, out, hist_part, scal);
  k_hr1  <<<128, 256, 0, stream>>>(hist_part, part2);
  k_fin  <<<1, 256, 0, stream>>>(part2, scal, aux);
}

// Round 11
// 69.589 us; speedup vs baseline: 2.0419x; 2.0419x over previous
//
#include <hip/hip_runtime.h>

#define M_ROWS 16384
#define DIMX   1024
#define CD     12
#define KCB    4096
#define PADW   60   // padded dwords per float4-position fragment (48 data + 12 pad)
#define NSLAB  512  // one hist slab per k_body block

// ---------- Kernel A: h = x @ W_in + b_in ; writes h and oidx ----------
// Arithmetic (FMA order k,e,d; butterfly ofs 1..32; +bin at end) is bit-identical
// to the round-1/2 version that produced exact index match. Also zeroes the two
// scalar accumulators (pse, com).
__global__ __launch_bounds__(256, 2) void k_hproj(
    const float* __restrict__ x, const float* __restrict__ Win,
    const float* __restrict__ bin, float* __restrict__ h, float* __restrict__ oidx,
    float* __restrict__ scal)
{
  if (blockIdx.x == 0 && threadIdx.x == 0) {
    scal[0] = 0.f; scal[1] = 0.f;   // pse, com
  }

  __shared__ __align__(16) float w[256 * PADW];   // 60 KB
  for (int f = threadIdx.x; f < 256 * 12; f += 256) {
    const int P = f / 12, c = f % 12;
    float4 v = reinterpret_cast<const float4*>(Win)[f];
    *reinterpret_cast<float4*>(&w[P * PADW + 4 * c]) = v;
  }
  __syncthreads();

  const int wave = threadIdx.x >> 6;
  const int lane = threadIdx.x & 63;
  const int g    = blockIdx.x * 4 + wave;         // 0..2047, 8 rows per wave

  float bb[CD];
#pragma unroll
  for (int d = 0; d < CD; ++d) bb[d] = bin[d];

  for (int it = 0; it < 4; ++it) {                // 2 rows per iteration
    const int row0 = g * 8 + it * 2;
    const float4* xr0 = reinterpret_cast<const float4*>(x + (size_t)row0 * DIMX);
    const float4* xr1 = reinterpret_cast<const float4*>(x + (size_t)(row0 + 1) * DIMX);
    float a0[CD], a1[CD];
#pragma unroll
    for (int d = 0; d < CD; ++d) { a0[d] = 0.f; a1[d] = 0.f; }

#pragma unroll
    for (int k = 0; k < 4; ++k) {
      const int P = lane + 64 * k;
      float4 xv0 = xr0[P];
      float4 xv1 = xr1[P];
      const float4* wf = reinterpret_cast<const float4*>(&w[P * PADW]);
      float4 wq[12];
#pragma unroll
      for (int c = 0; c < 12; ++c) wq[c] = wf[c];
      const float* wfl = reinterpret_cast<const float*>(wq);
      float xe0[4] = {xv0.x, xv0.y, xv0.z, xv0.w};
      float xe1[4] = {xv1.x, xv1.y, xv1.z, xv1.w};
#pragma unroll
      for (int e = 0; e < 4; ++e)
#pragma unroll
        for (int d = 0; d < CD; ++d) {
          const float wv = wfl[e * CD + d];
          a0[d] = fmaf(xe0[e], wv, a0[d]);
          a1[d] = fmaf(xe1[e], wv, a1[d]);
        }
    }
#pragma unroll
    for (int ofs = 1; ofs < 64; ofs <<= 1)
#pragma unroll
      for (int d = 0; d < CD; ++d) {
        a0[d] += __shfl_xor(a0[d], ofs, 64);
        a1[d] += __shfl_xor(a1[d], ofs, 64);
      }

    if (lane == 0) {
      int i0 = 0, i1 = 0;
#pragma unroll
      for (int d = 0; d < CD; ++d) {
        const float h0 = a0[d] + bb[d];
        const float h1 = a1[d] + bb[d];
        h[(size_t)row0 * CD + d]       = h0;
        h[(size_t)(row0 + 1) * CD + d] = h1;
        i0 |= (h0 > 0.f) ? (1 << d) : 0;
        i1 |= (h1 > 0.f) ? (1 << d) : 0;
      }
      oidx[row0]     = (float)i0;
      oidx[row0 + 1] = (float)i1;
    }
  }
}

// ---------- Kernel B: fused out-projection + entropy/commit + histogram ----------
// 512 threads, 32 rows per block.
// Phase 0: q = sigmoid(40h) once per block -> LDS sq[32][16]; pse/com reduced
//          per-wave into LDS partials (NO global atomics here — round-10 lesson:
//          6 same-line atomics/block trapped behind __syncthreads' vmcnt(0)
//          serialized device-wide and cost ~60 us).
// Phase A: thread owns 2 output cols (wreg = 24 regs).
// Phase B: 8 waves; wave w owns hist m in [8w, 8w+8): per row 3 broadcast
//          ds_read_b128 + straight-line trees + 8 FMA.
// End: thread 0 issues the block's single atomicAdd pair — fire-and-forget,
//      never waited on by any barrier (round-9 pattern).
__global__ __launch_bounds__(512) void k_body(
    const float* __restrict__ h, const float* __restrict__ Wout,
    const float* __restrict__ bout, const float* __restrict__ oidx,
    float* __restrict__ out, float* __restrict__ hist_part,
    float* __restrict__ scal)
{
  __shared__ __align__(16) float sq[32 * 16];    // q[row][d], row-padded to 16
  __shared__ float pp[8], cc[8];
  const int t    = threadIdx.x;          // 0..511
  const int bid  = blockIdx.x;
  const int row0 = bid * 32;

  // ---------------- Phase 0: q-tree once per block ----------------
  if (t < 384) {                          // waves 0..5, one (row,d) per thread
    const float hv  = h[(size_t)row0 * CD + t];   // coalesced 384 floats
    const float ax  = fabsf(40.f * hv);
    const float e2  = __expf(-ax);
    const float s1  = 1.f + e2;
    const float inv = 1.f / s1;
    const float qv  = (hv > 0.f) ? inv : e2 * inv;          // sigmoid(40 h)
    sq[(t / 12) * 16 + (t % 12)] = qv;
    float pse_c = __logf(s1) + ax * e2 * inv;               // per-dim entropy
    const float dd = fabsf(hv) - 1.f;
    float com_c = dd * dd;
#pragma unroll
    for (int ofs = 1; ofs < 64; ofs <<= 1) {
      pse_c += __shfl_xor(pse_c, ofs, 64);
      com_c += __shfl_xor(com_c, ofs, 64);
    }
    if ((t & 63) == 0) { pp[t >> 6] = pse_c; cc[t >> 6] = com_c; }
  }

  // ---------------- Phase A: out = sign(h) @ W_out + b_out ----------------
  {
    float w0[CD], w1[CD];
#pragma unroll
    for (int d = 0; d < CD; ++d) {
      float2 v = *reinterpret_cast<const float2*>(Wout + d * DIMX + 2 * t);
      w0[d] = v.x; w1[d] = v.y;
    }
    const float2 b2 = *reinterpret_cast<const float2*>(bout + 2 * t);

    for (int i = 0; i < 32; ++i) {
      const int row = row0 + i;
      const int idx = (int)oidx[row];    // block-uniform scalar load
      float o0 = b2.x, o1 = b2.y;
#pragma unroll
      for (int d = 0; d < CD; ++d) {
        const float s = ((idx >> d) & 1) ? 1.f : -1.f;
        o0 = fmaf(s, w0[d], o0);
        o1 = fmaf(s, w1[d], o1);
      }
      *reinterpret_cast<float2*>(out + (size_t)row * DIMX + 2 * t) = make_float2(o0, o1);
    }
  }

  __syncthreads();                        // sq + pp/cc ready for all waves

  // ---------------- Phase B: factorized histogram ----------------
  const int lane = t & 63;
  const int w8   = t >> 6;                // wave id 0..7; m in [8*w8, 8*w8+8)

  float c0=0.f,c1=0.f,c2=0.f,c3=0.f,c4=0.f,c5=0.f,c6=0.f,c7=0.f;

  for (int i = 0; i < 32; ++i) {
    const float4 qa = *reinterpret_cast<const float4*>(&sq[i * 16]);      // q0..q3
    const float4 qb = *reinterpret_cast<const float4*>(&sq[i * 16 + 4]);  // q4..q7
    const float4 qc = *reinterpret_cast<const float4*>(&sq[i * 16 + 8]);  // q8..q11

    // A over the low 6 bits (lane-dependent)
    float A = ((lane >> 0) & 1) ? qa.x : 1.f - qa.x;
    A      *= ((lane >> 1) & 1) ? qa.y : 1.f - qa.y;
    A      *= ((lane >> 2) & 1) ? qa.z : 1.f - qa.z;
    A      *= ((lane >> 3) & 1) ? qa.w : 1.f - qa.w;
    A      *= ((lane >> 4) & 1) ? qb.x : 1.f - qb.x;
    A      *= ((lane >> 5) & 1) ? qb.y : 1.f - qb.y;

    // E = A * C over dims 6..8
    const float t6 = 1.f - qb.z, t7 = 1.f - qb.w, t8 = 1.f - qc.x;
    const float u0 = t6 * t7, u1 = qb.z * t7, u2 = t6 * qb.w, u3 = qb.z * qb.w;
    const float E0 = A * (u0 * t8),   E1 = A * (u1 * t8),   E2 = A * (u2 * t8),   E3 = A * (u3 * t8);
    const float E4 = A * (u0 * qc.x), E5 = A * (u1 * qc.x), E6 = A * (u2 * qc.x), E7 = A * (u3 * qc.x);

    // this wave's single D value over dims 9..11 (m>>3 == w8)
    const float vw = (((w8 & 1) ? qc.y : 1.f - qc.y) * ((w8 & 2) ? qc.z : 1.f - qc.z));
    const float Dw = vw * ((w8 & 4) ? qc.w : 1.f - qc.w);

    c0 = fmaf(E0, Dw, c0); c1 = fmaf(E1, Dw, c1); c2 = fmaf(E2, Dw, c2); c3 = fmaf(E3, Dw, c3);
    c4 = fmaf(E4, Dw, c4); c5 = fmaf(E5, Dw, c5); c6 = fmaf(E6, Dw, c6); c7 = fmaf(E7, Dw, c7);
  }

  // disjoint coalesced slab write: index = (8*w8 + e)*64 + lane
  float* hp = hist_part + (size_t)bid * KCB + (size_t)w8 * 512 + lane;
  hp[0*64] = c0; hp[1*64] = c1; hp[2*64] = c2; hp[3*64] = c3;
  hp[4*64] = c4; hp[5*64] = c5; hp[6*64] = c6; hp[7*64] = c7;

  // single fire-and-forget atomic pair per block, issued last (no barrier after)
  if (t == 0) {
    const float ps = pp[0] + pp[1] + pp[2] + pp[3] + pp[4] + pp[5];
    const float cs = cc[0] + cc[1] + cc[2] + cc[3] + cc[4] + cc[5];
    atomicAdd(&scal[0], ps);
    atomicAdd(&scal[1], cs);
  }
}

// ---------- Kernel C: stage-1 slab reduction (128 blocks) ----------
__global__ __launch_bounds__(256) void k_hr1(
    const float* __restrict__ hist_part, float* __restrict__ part2)
{
  const int j0    = (blockIdx.x & 7) * 512 + threadIdx.x;
  const int chunk = blockIdx.x >> 3;              // 0..15
  const int s0    = chunk * (NSLAB / 16);
  float acc0 = 0.f, acc1 = 0.f;
#pragma unroll 4
  for (int s = 0; s < NSLAB / 16; ++s) {
    const float* hp = hist_part + (size_t)(s0 + s) * KCB;
    acc0 += hp[j0];
    acc1 += hp[j0 + 256];
  }
  part2[(size_t)chunk * KCB + j0]       = acc0;
  part2[(size_t)chunk * KCB + j0 + 256] = acc1;
}

// ---------- Kernel D: final codebook entropy + aux (single block) ----------
__global__ __launch_bounds__(256) void k_fin(
    const float* __restrict__ part2, const float* __restrict__ scal,
    float* __restrict__ aux)
{
  const int t = threadIdx.x;
  float term = 0.f;
#pragma unroll
  for (int k = 0; k < 16; ++k) {
    const int j = t + 256 * k;
    float a = 0.f;
#pragma unroll
    for (int c = 0; c < 16; ++c) a += part2[(size_t)c * KCB + j];
    a *= (1.f / 16384.f);
    term -= a * __logf(a + 1e-10f);
  }
#pragma unroll
  for (int ofs = 1; ofs < 64; ofs <<= 1) term += __shfl_xor(term, ofs, 64);
  __shared__ float sw[4];
  if ((t & 63) == 0) sw[t >> 6] = term;
  __syncthreads();
  if (t == 0) {
    const float cbe = sw[0] + sw[1] + sw[2] + sw[3];
    aux[0] = scal[0] * (1.f / 16384.f) - cbe + scal[1] * (1.f / 196608.f);
  }
}

extern "C" void kernel_launch(void* const* d_in, const int* in_sizes, int n_in,
                              void* d_out, int out_size, void* d_ws, size_t ws_size,
                              hipStream_t stream)
{
  const float* x    = (const float*)d_in[0];
  const float* Win  = (const float*)d_in[1];
  const float* bin  = (const float*)d_in[2];
  const float* Wout = (const float*)d_in[3];
  const float* bout = (const float*)d_in[4];

  float* out  = (float*)d_out;                       // [16384 x 1024]
  float* oidx = out + (size_t)M_ROWS * DIMX;         // [16384]
  float* aux  = oidx + M_ROWS;                       // [1]

  float* ws        = (float*)d_ws;
  float* h         = ws;                             // 196608 floats
  float* scal      = ws + (size_t)M_ROWS * CD;       // pse, com (pad 16)
  float* part2     = scal + 16;                      // 16 * 4096 floats
  float* hist_part = part2 + 16 * KCB;               // NSLAB * 4096 floats

  k_hproj<<<512, 256, 0, stream>>>(x, Win, bin, h, oidx, scal);
  k_body <<<NSLAB, 512, 0, stream>>>(h, Wout, bout, oidx, out, hist_part, scal);
  k_hr1  <<<128, 256, 0, stream>>>(hist_part, part2);
  k_fin  <<<1, 256, 0, stream>>>(part2, scal, aux);
}